// Round 1
// baseline (11204.015 us; speedup 1.0000x reference)
//
#include <hip/hip_runtime.h>
#include <stdint.h>

typedef unsigned long long u64;

#define NBATCH 32
#define NPTS   131072
#define KBLK   8                 // blocks per batch
#define PPB    (NPTS / KBLK)     // 16384 points per block
#define NTHR   512
#define PPT    (PPB / NTHR)      // 32 points per thread
#define FLT_MAX_C 3.402823466e+38f

// Slot layout in d_ws: one 64B-padded u64 per (batch, block, parity).
// Packed word: [63:49]=tag(step), [48:17]=float bits of best dist (>=0 so
// monotone as uint), [16:0]=131071-idx (so bigger packed == smaller idx on
// dist ties -> first-occurrence argmax, matching np.argmax).
__device__ __forceinline__ u64* slot_ptr(u64* slots, int b, int k, int par) {
    return slots + (((size_t)(b * KBLK + k) * 2) + par) * 8;  // *8 u64 = 64B stride
}

__global__ __launch_bounds__(NTHR, 2)
void fps_kernel(const float* __restrict__ points, int* __restrict__ out,
                u64* __restrict__ slots, int S)
{
    const int b    = blockIdx.x & (NBATCH - 1);  // batch: &31 keeps a batch's 8
    const int kk   = blockIdx.x >> 5;            // blocks on one XCD (i%8 map)
    const int t    = threadIdx.x;
    const int lane = t & 63;
    const int wv   = t >> 6;

    const float* pb = points + (size_t)b * 3 * NPTS;
    const float* bx = pb + kk * PPB;
    const float* by = bx + NPTS;
    const float* bz = bx + 2 * NPTS;

    // All per-point state lives in registers for the whole kernel.
    float px[PPT], py[PPT], pz[PPT], md[PPT];
    const int t4 = t * 4;

#pragma unroll
    for (int c = 0; c < PPT / 4; ++c) {
        float4 vx = *(const float4*)(bx + c * (NTHR * 4) + t4);
        float4 vy = *(const float4*)(by + c * (NTHR * 4) + t4);
        float4 vz = *(const float4*)(bz + c * (NTHR * 4) + t4);
        px[c*4+0]=vx.x; px[c*4+1]=vx.y; px[c*4+2]=vx.z; px[c*4+3]=vx.w;
        py[c*4+0]=vy.x; py[c*4+1]=vy.y; py[c*4+2]=vy.z; py[c*4+3]=vy.w;
        pz[c*4+0]=vz.x; pz[c*4+1]=vz.y; pz[c*4+2]=vz.z; pz[c*4+3]=vz.w;
        md[c*4+0]=FLT_MAX_C; md[c*4+1]=FLT_MAX_C;
        md[c*4+2]=FLT_MAX_C; md[c*4+3]=FLT_MAX_C;
    }

    __shared__ float s_v[8];
    __shared__ int   s_i[8];
    __shared__ int   s_idx;

    // Centroid 0 is point 0 (reference semantics); out[b][0] = 0.
    float cx = pb[0], cy = pb[NPTS], cz = pb[2 * NPTS];
    if (kk == 0 && t == 0) out[(size_t)b * S] = 0;

    for (int s = 1; s < S; ++s) {
        float bestv = -1.0f;
        int   bestp = 0;
        // Pure-VALU scan: exact np fp32 semantics (no fma contraction),
        // ascending-index order so strict '>' keeps the first max.
#pragma unroll
        for (int p = 0; p < PPT; ++p) {
            float dx = __fsub_rn(px[p], cx);
            float dy = __fsub_rn(py[p], cy);
            float dz = __fsub_rn(pz[p], cz);
            float d  = __fadd_rn(__fadd_rn(__fmul_rn(dx, dx), __fmul_rn(dy, dy)),
                                 __fmul_rn(dz, dz));
            float m  = fminf(md[p], d);
            md[p] = m;
            bool tk = m > bestv;
            bestv = tk ? m : bestv;
            bestp = tk ? p : bestp;
        }
        int gidx = kk * PPB + (bestp >> 2) * (NTHR * 4) + t4 + (bestp & 3);

        // Wave reduce (64 lanes), tie -> lower index.
#pragma unroll
        for (int off = 32; off >= 1; off >>= 1) {
            float ov = __shfl_down(bestv, off);
            int   oi = __shfl_down(gidx, off);
            bool tk = (ov > bestv) || (ov == bestv && oi < gidx);
            bestv = tk ? ov : bestv;
            gidx  = tk ? oi : gidx;
        }
        if (lane == 0) { s_v[wv] = bestv; s_i[wv] = gidx; }
        __syncthreads();

        if (wv == 0) {
            // Cross-wave reduce (8 waves) in wave 0.
            float v8 = (lane < 8) ? s_v[lane] : -1.0f;
            int   i8 = (lane < 8) ? s_i[lane] : 0x7fffffff;
#pragma unroll
            for (int off = 4; off >= 1; off >>= 1) {
                float ov = __shfl_down(v8, off);
                int   oi = __shfl_down(i8, off);
                bool tk = (ov > v8) || (ov == v8 && oi < i8);
                v8 = tk ? ov : v8;
                i8 = tk ? oi : i8;
            }
            if (lane == 0) {
                u64 my = ((u64)(unsigned)s << 49)
                       | ((u64)__float_as_uint(v8) << 17)
                       | (u64)(unsigned)(131071 - i8);
                __hip_atomic_store(slot_ptr(slots, b, kk, s & 1), my,
                                   __ATOMIC_RELEASE, __HIP_MEMORY_SCOPE_AGENT);
            }
            // Lanes 0..7 poll the 8 partials (exact tag match: 0xAA poison
            // tag = 21845 and stale tag = s-2 both keep spinning; skew<=1
            // proof makes parity double-buffer overwrite-safe).
            u64 got = 0;
            if (lane < KBLK) {
                u64* ps = slot_ptr(slots, b, lane, s & 1);
                do {
                    got = __hip_atomic_load(ps, __ATOMIC_ACQUIRE,
                                            __HIP_MEMORY_SCOPE_AGENT);
                } while ((int)(got >> 49) != s);
            }
#pragma unroll
            for (int off = 4; off >= 1; off >>= 1) {
                u64 og = __shfl_down(got, off);
                got = og > got ? og : got;
            }
            if (lane == 0) {
                int idx = 131071 - (int)(got & 0x1FFFF);
                s_idx = idx;
                if (kk == 0) out[(size_t)b * S + s] = idx;
            }
        }
        __syncthreads();
        int idx = s_idx;
        // Wave-uniform broadcast loads of the new centroid (L2/L3-hot).
        cx = pb[idx];
        cy = pb[NPTS + idx];
        cz = pb[2 * NPTS + idx];
    }
}

extern "C" void kernel_launch(void* const* d_in, const int* in_sizes, int n_in,
                              void* d_out, int out_size, void* d_ws, size_t ws_size,
                              hipStream_t stream) {
    const float* points = (const float*)d_in[0];
    int* out   = (int*)d_out;
    u64* slots = (u64*)d_ws;              // needs 32*8*2*64B = 32 KB
    int S = out_size / NBATCH;            // 2048; avoids device read of d_in[1]
    // 256 blocks x 8 waves, <=256 VGPRs (launch_bounds 512,2) -> exactly
    // 1 block/CU on 256 CUs: full grid co-resident, spin-exchange is safe.
    fps_kernel<<<dim3(NBATCH * KBLK), dim3(NTHR), 0, stream>>>(points, out, slots, S);
}

// Round 2
// 7101.035 us; speedup vs baseline: 1.5778x; 1.5778x over previous
//
#include <hip/hip_runtime.h>
#include <stdint.h>

typedef unsigned long long u64;

#define NBATCH 32
#define NPTS   131072
#define KBLK   8                 // blocks per batch
#define PPB    (NPTS / KBLK)     // 16384 points per block (2^14)
#define NTHR   1024
#define NWAVE  (NTHR / 64)       // 16 waves
#define PPT    (PPB / NTHR)      // 16 points per thread
#define FLT_MAX_C 3.402823466e+38f

// ws: per (batch, block, parity) one 64B slot of 8 u64.
// words 0..2: ((u64)s<<32) | float_bits(x|y|z)   -- self-tagged, relaxed
// word  3   : ((u64)s<<49) | dist_bits<<17 | (131071-idx)
//   (dist>=0 -> float bits monotone as uint; idx inverted so u64-max gives
//    first-occurrence argmax, matching np.argmax tie-break.)
// 0xAA poison: word tag 0xAAAAAAAA / 21845 never equals s<2048 -> no ws init.
__device__ __forceinline__ u64* slot_ptr(u64* slots, int b, int k, int par) {
    return slots + ((size_t)((b * KBLK + k) * 2 + par)) * 8;
}

__global__ __launch_bounds__(NTHR, 4)   // cap 128 VGPR: 16-wave block fits 1/CU
void fps_kernel(const float* __restrict__ points, int* __restrict__ out,
                u64* __restrict__ slots, int S)
{
    const int b    = blockIdx.x & (NBATCH - 1);
    const int kk   = blockIdx.x >> 5;
    const int t    = threadIdx.x;
    const int lane = t & 63;
    const int wv   = t >> 6;

    const float* pb = points + (size_t)b * 3 * NPTS;
    const float* bx = pb + kk * PPB;
    const float* by = bx + NPTS;
    const float* bz = bx + 2 * NPTS;

    // 64 floats of persistent state per thread -> real VGPRs (<=128 cap).
    float px[PPT], py[PPT], pz[PPT], md[PPT];
    const int t4 = t * 4;
#pragma unroll
    for (int c = 0; c < PPT / 4; ++c) {
        float4 vx = *(const float4*)(bx + c * (NTHR * 4) + t4);
        float4 vy = *(const float4*)(by + c * (NTHR * 4) + t4);
        float4 vz = *(const float4*)(bz + c * (NTHR * 4) + t4);
        px[c*4+0]=vx.x; px[c*4+1]=vx.y; px[c*4+2]=vx.z; px[c*4+3]=vx.w;
        py[c*4+0]=vy.x; py[c*4+1]=vy.y; py[c*4+2]=vy.z; py[c*4+3]=vy.w;
        pz[c*4+0]=vz.x; pz[c*4+1]=vz.y; pz[c*4+2]=vz.z; pz[c*4+3]=vz.w;
        md[c*4+0]=FLT_MAX_C; md[c*4+1]=FLT_MAX_C;
        md[c*4+2]=FLT_MAX_C; md[c*4+3]=FLT_MAX_C;
    }

    __shared__ float s_v[NWAVE];
    __shared__ int   s_i[NWAVE];
    __shared__ int   s_bi;          // block-winner idx (for owner extract)
    __shared__ unsigned s_bc[4];    // next centroid xbits,ybits,zbits,idx

    float cx = pb[0], cy = pb[NPTS], cz = pb[2 * NPTS];
    if (kk == 0 && t == 0) out[(size_t)b * S] = 0;

    for (int s = 1; s < S; ++s) {
        // ---- scan: exact np fp32 semantics (no fma), ascending-index '>'
        float bestv = -1.0f;
        int   bestp = 0;
#pragma unroll
        for (int p = 0; p < PPT; ++p) {
            float dx = __fsub_rn(px[p], cx);
            float dy = __fsub_rn(py[p], cy);
            float dz = __fsub_rn(pz[p], cz);
            float d  = __fadd_rn(__fadd_rn(__fmul_rn(dx, dx), __fmul_rn(dy, dy)),
                                 __fmul_rn(dz, dz));
            float m  = fminf(md[p], d);
            md[p] = m;
            bool tk = m > bestv;
            bestv = tk ? m : bestv;
            bestp = tk ? p : bestp;
        }
        int gidx = kk * PPB + (bestp >> 2) * (NTHR * 4) + t4 + (bestp & 3);

        // ---- wave reduce, tie -> lower index
#pragma unroll
        for (int off = 32; off >= 1; off >>= 1) {
            float ov = __shfl_down(bestv, off);
            int   oi = __shfl_down(gidx, off);
            bool tk = (ov > bestv) || (ov == bestv && oi < gidx);
            bestv = tk ? ov : bestv;
            gidx  = tk ? oi : gidx;
        }
        if (lane == 0) { s_v[wv] = bestv; s_i[wv] = gidx; }
        __syncthreads();

        // ---- cross-wave reduce in wave 0; publish di word (relaxed)
        if (wv == 0) {
            float v16 = (lane < NWAVE) ? s_v[lane] : -1.0f;
            int   i16 = (lane < NWAVE) ? s_i[lane] : 0x7fffffff;
#pragma unroll
            for (int off = 8; off >= 1; off >>= 1) {
                float ov = __shfl_down(v16, off);
                int   oi = __shfl_down(i16, off);
                bool tk = (ov > v16) || (ov == v16 && oi < i16);
                v16 = tk ? ov : v16;
                i16 = tk ? oi : i16;
            }
            if (lane == 0) {
                u64 di = ((u64)(unsigned)s << 49)
                       | ((u64)__float_as_uint(v16) << 17)
                       | (u64)(unsigned)(131071 - i16);
                __hip_atomic_store(slot_ptr(slots, b, kk, s & 1) + 3, di,
                                   __ATOMIC_RELAXED, __HIP_MEMORY_SCOPE_AGENT);
                s_bi = i16;
            }
        }
        __syncthreads();

        // ---- owner thread ships the block-winner coords (self-tagged words)
        int widx = s_bi;
        if ((widx >> 14) == kk) {
            int l = widx & (PPB - 1);
            if (t == ((l >> 2) & (NTHR - 1))) {
                int pw = ((l >> 12) << 2) | (l & 3);   // c*4 + j
                float wx = 0.f, wy = 0.f, wz = 0.f;
#pragma unroll
                for (int p = 0; p < PPT; ++p) {        // constant-index select
                    bool e = (p == pw);
                    wx = e ? px[p] : wx; wy = e ? py[p] : wy; wz = e ? pz[p] : wz;
                }
                u64 tg = (u64)(unsigned)s << 32;
                u64* sp = slot_ptr(slots, b, kk, s & 1);
                __hip_atomic_store(sp + 0, tg | __float_as_uint(wx),
                                   __ATOMIC_RELAXED, __HIP_MEMORY_SCOPE_AGENT);
                __hip_atomic_store(sp + 1, tg | __float_as_uint(wy),
                                   __ATOMIC_RELAXED, __HIP_MEMORY_SCOPE_AGENT);
                __hip_atomic_store(sp + 2, tg | __float_as_uint(wz),
                                   __ATOMIC_RELAXED, __HIP_MEMORY_SCOPE_AGENT);
            }
        }

        // ---- wave 0: poll all 8 blocks' 4 words (relaxed, tag-matched)
        if (wv == 0) {
            u64 got = 0;
            if (lane < 32) {
                u64* ps = slot_ptr(slots, b, lane >> 2, s & 1) + (lane & 3);
                const int sh = ((lane & 3) == 3) ? 49 : 32;
                do {
                    got = __hip_atomic_load(ps, __ATOMIC_RELAXED,
                                            __HIP_MEMORY_SCOPE_AGENT);
                } while ((int)(got >> sh) != s);
            }
            // select winning block by u64-max of di words (unique: idx in low bits)
            u64 dval = (u64)__shfl((long long)got, lane * 4 + 3);
            u64 dv = (lane < 8) ? dval : 0ull;
#pragma unroll
            for (int off = 4; off >= 1; off >>= 1) {
                u64 o = (u64)__shfl_down((long long)dv, off);
                dv = (o > dv) ? o : dv;
            }
            u64 win = (u64)__shfl((long long)dv, 0);
            u64 mask = __ballot(lane < 8 && dval == win);
            int w = __ffsll(mask) - 1;
            unsigned lo = (unsigned)got;
            unsigned cxb = (unsigned)__shfl((int)lo, w * 4 + 0);
            unsigned cyb = (unsigned)__shfl((int)lo, w * 4 + 1);
            unsigned czb = (unsigned)__shfl((int)lo, w * 4 + 2);
            int idx = 131071 - (int)(win & 0x1FFFF);
            if (lane == 0) {
                s_bc[0] = cxb; s_bc[1] = cyb; s_bc[2] = czb; s_bc[3] = (unsigned)idx;
                if (kk == 0) out[(size_t)b * S + s] = idx;
            }
        }
        __syncthreads();
        cx = __uint_as_float(s_bc[0]);
        cy = __uint_as_float(s_bc[1]);
        cz = __uint_as_float(s_bc[2]);
    }
}

extern "C" void kernel_launch(void* const* d_in, const int* in_sizes, int n_in,
                              void* d_out, int out_size, void* d_ws, size_t ws_size,
                              hipStream_t stream) {
    const float* points = (const float*)d_in[0];
    int* out   = (int*)d_out;
    u64* slots = (u64*)d_ws;              // 32*8*2*64B = 32 KB
    int S = out_size / NBATCH;            // 2048
    // 256 blocks x 16 waves -> exactly 1 block/CU on 256 CUs: co-resident.
    fps_kernel<<<dim3(NBATCH * KBLK), dim3(NTHR), 0, stream>>>(points, out, slots, S);
}